// Round 2
// baseline (570.621 us; speedup 1.0000x reference)
//
#include <hip/hip_runtime.h>
#include <hip/hip_bf16.h>

#define TSEQ 2048
#define TBZ  32
#define TDIM 1024

typedef __attribute__((ext_vector_type(8))) short bf16x8;
typedef __attribute__((ext_vector_type(4))) float f32x4;

constexpr int BM = 128, BN = 128, BK = 64;
// LDS rows are 128 B (64 bf16), XOR-swizzled: chunk c16 at row r lives at
// byte r*128 + ((c16 ^ (r&7)) << 4).  Write-side and read-side use the same
// involution (both-sides rule, guide §5 note 21). 16-lane groups then hit 8
// distinct bank quads x2 lanes = 2-way = free (m136).

__device__ inline unsigned int pk2(float lo, float hi) {
    __hip_bfloat162 h = __float22bfloat162_rn(make_float2(lo, hi)); // v_cvt_pk_bf16_f32
    return *reinterpret_cast<const unsigned int*>(&h);
}

__global__ __launch_bounds__(256) void mapper_gemm(
    const float* __restrict__ x, const int* __restrict__ lang_ids,
    const float* __restrict__ W, const float* __restrict__ bias,
    float* __restrict__ out)
{
    // XCD-chunked bijective swizzle: 4096 = 8 XCDs x 512 logical blocks.
    // Logical order: b (col) major, then m-tile, then n-tile fastest, so the
    // 8 blocks sharing an x-panel are consecutive -> same XCD L2.
    const int p  = blockIdx.x;
    const int l  = (p & 7) * 512 + (p >> 3);
    const int b  = l >> 7;
    const int mt = (l >> 3) & 15;
    const int nt = l & 7;
    const int s0 = mt * BM;
    const int e0 = nt * BN;
    const int tid = threadIdx.x;

    const int lid    = lang_ids[b];
    const int gid    = 8 - lid;
    const bool active = (gid >= 1) && (gid <= 8);
    int eb = gid - 1; eb = eb < 0 ? 0 : (eb > 7 ? 7 : eb);

    if (!active) {
        const f32x4* xs = (const f32x4*)x;
        f32x4*       os = (f32x4*)out;
        const int rowstride4 = TBZ * TDIM / 4;
        for (int i = tid; i < (BM * BN) / 4; i += 256) {
            int r = i >> 5;
            int c = i & 31;
            long idx = (long)(s0 + r) * rowstride4 + b * (TDIM / 4) + (e0 >> 2) + c;
            os[idx] = xs[idx];
        }
        return;
    }

    __shared__ unsigned char AsB[BM * 128];   // 16 KB, bf16 [128][64] swizzled
    __shared__ unsigned char BsB[BN * 128];   // 16 KB

    const float* __restrict__ Wb = W + (long)eb * TDIM * TDIM;

    const int lane = tid & 63;
    const int wave = tid >> 6;
    const int wr   = wave >> 1;        // 2x2 wave grid, 64x64 out each
    const int wc   = wave & 1;
    const int fr   = lane & 15;

    f32x4 acc[4][4];
    #pragma unroll
    for (int m = 0; m < 4; ++m)
        #pragma unroll
        for (int n = 0; n < 4; ++n)
            acc[m][n] = (f32x4){0.f, 0.f, 0.f, 0.f};

    // staging: 256 threads cover 128 rows x 64 f32; 2 threads/row, 32 f32 each
    const int rg = tid >> 1;           // row 0..127
    const int hh = tid & 1;            // half: cols hh*32 .. hh*32+31
    const float* aSrc = x  + (long)(s0 + rg) * (TBZ * TDIM) + b * TDIM + hh * 32;
    const float* bSrc = Wb + (long)(e0 + rg) * TDIM + hh * 32;
    const int wrowA = rg * 128;        // LDS row byte base
    const int rsw   = (rg & 7);        // swizzle key

    f32x4 ar[8], br[8];

    #define LOADK(K0)                                                  \
        _Pragma("unroll")                                              \
        for (int j = 0; j < 8; ++j) {                                  \
            ar[j] = *(const f32x4*)(aSrc + (K0) + j * 4);              \
            br[j] = *(const f32x4*)(bSrc + (K0) + j * 4);              \
        }

    #define STOREK()                                                   \
        _Pragma("unroll")                                              \
        for (int cc = 0; cc < 4; ++cc) {                               \
            uint4 av, bv;                                              \
            av.x = pk2(ar[2*cc].x,   ar[2*cc].y);                      \
            av.y = pk2(ar[2*cc].z,   ar[2*cc].w);                      \
            av.z = pk2(ar[2*cc+1].x, ar[2*cc+1].y);                    \
            av.w = pk2(ar[2*cc+1].z, ar[2*cc+1].w);                    \
            bv.x = pk2(br[2*cc].x,   br[2*cc].y);                      \
            bv.y = pk2(br[2*cc].z,   br[2*cc].w);                      \
            bv.z = pk2(br[2*cc+1].x, br[2*cc+1].y);                    \
            bv.w = pk2(br[2*cc+1].z, br[2*cc+1].w);                    \
            const int c16 = hh * 4 + cc;                               \
            const int off = wrowA + ((c16 ^ rsw) << 4);                \
            *(uint4*)(AsB + off) = av;                                 \
            *(uint4*)(BsB + off) = bv;                                 \
        }

    LOADK(0);
    for (int k0 = 0; k0 < TDIM; k0 += BK) {
        __syncthreads();               // previous iter's readers done
        STOREK();
        if (k0 + BK < TDIM) { LOADK(k0 + BK); }  // overlap with MFMA below
        __syncthreads();

        #pragma unroll
        for (int kk = 0; kk < 2; ++kk) {
            const int cbase = kk * 4 + (lane >> 4);
            bf16x8 af[4], bfm[4];
            #pragma unroll
            for (int m = 0; m < 4; ++m) {
                const int row = wr * 64 + m * 16 + fr;
                af[m] = *(const bf16x8*)(AsB + row * 128 + ((cbase ^ (row & 7)) << 4));
            }
            #pragma unroll
            for (int n = 0; n < 4; ++n) {
                const int row = wc * 64 + n * 16 + fr;
                bfm[n] = *(const bf16x8*)(BsB + row * 128 + ((cbase ^ (row & 7)) << 4));
            }
            #pragma unroll
            for (int m = 0; m < 4; ++m)
                #pragma unroll
                for (int n = 0; n < 4; ++n)
                    acc[m][n] = __builtin_amdgcn_mfma_f32_16x16x32_bf16(af[m], bfm[n], acc[m][n], 0, 0, 0);
        }
    }

    // epilogue: C/D layout col=lane&15, row=(lane>>4)*4+j  [verified m89/m91]
    const int cr = lane >> 4;
    const int cc = lane & 15;
    #pragma unroll
    for (int n = 0; n < 4; ++n) {
        const int e  = e0 + wc * 64 + n * 16 + cc;
        const float bv = bias[eb * TDIM + e];
        #pragma unroll
        for (int m = 0; m < 4; ++m) {
            #pragma unroll
            for (int j = 0; j < 4; ++j) {
                const int s = s0 + wr * 64 + m * 16 + cr * 4 + j;
                out[(long)s * (TBZ * TDIM) + b * TDIM + e] = acc[m][n][j] + bv;
            }
        }
    }
    #undef LOADK
    #undef STOREK
}

extern "C" void kernel_launch(void* const* d_in, const int* in_sizes, int n_in,
                              void* d_out, int out_size, void* d_ws, size_t ws_size,
                              hipStream_t stream) {
    const float* x        = (const float*)d_in[0];
    const int*   lang_ids = (const int*)d_in[1];
    const float* W        = (const float*)d_in[2];
    const float* bias     = (const float*)d_in[3];
    float*       out      = (float*)d_out;

    const int grid = TBZ * (TSEQ / BM) * (TDIM / BN);   // 4096
    mapper_gemm<<<grid, 256, 0, stream>>>(x, lang_ids, W, bias, out);
}

// Round 3
// 366.305 us; speedup vs baseline: 1.5578x; 1.5578x over previous
//
#include <hip/hip_runtime.h>
#include <hip/hip_bf16.h>

#define TSEQ 2048
#define TBZ  32
#define TDIM 1024
#define NLS  8

typedef __attribute__((ext_vector_type(8))) short bf16x8;
typedef __attribute__((ext_vector_type(4))) float f32x4;

__device__ inline unsigned int pk2(float lo, float hi) {
    __hip_bfloat162 h = __float22bfloat162_rn(make_float2(lo, hi)); // v_cvt_pk_bf16_f32
    return *reinterpret_cast<const unsigned int*>(&h);
}

__device__ inline void gload_lds16(const void* g, void* l) {
    __builtin_amdgcn_global_load_lds(
        (const __attribute__((address_space(1))) unsigned int*)g,
        (__attribute__((address_space(3))) unsigned int*)l,
        16, 0, 0);
}

// ---------- pass 1a: x [s][b][d] f32 -> xb [b][s][d] bf16 ----------
__global__ __launch_bounds__(256) void conv_x(const float* __restrict__ x,
                                              unsigned short* __restrict__ xb) {
    const int total = TSEQ * TBZ * TDIM / 8;       // 8M chunks of 8
    const int stride = gridDim.x * 256;
    for (int i = blockIdx.x * 256 + threadIdx.x; i < total; i += stride) {
        const int d8  = i & (TDIM / 8 - 1);        // 0..127
        const int row = i >> 7;                    // s*TBZ + b
        const int s   = row >> 5;
        const int b   = row & (TBZ - 1);
        const float* src = x + (long)row * TDIM + d8 * 8;
        f32x4 v0 = *(const f32x4*)(src);
        f32x4 v1 = *(const f32x4*)(src + 4);
        uint4 o;
        o.x = pk2(v0.x, v0.y); o.y = pk2(v0.z, v0.w);
        o.z = pk2(v1.x, v1.y); o.w = pk2(v1.z, v1.w);
        *(uint4*)(xb + (long)(b * TSEQ + s) * TDIM + d8 * 8) = o;
    }
}

// ---------- pass 1b: W f32 -> bf16 (same layout) ----------
__global__ __launch_bounds__(256) void conv_w(const float* __restrict__ W,
                                              unsigned short* __restrict__ wb) {
    const int total = NLS * TDIM * TDIM / 8;       // 1M chunks
    const int stride = gridDim.x * 256;
    for (int i = blockIdx.x * 256 + threadIdx.x; i < total; i += stride) {
        const float* src = W + (long)i * 8;
        f32x4 v0 = *(const f32x4*)(src);
        f32x4 v1 = *(const f32x4*)(src + 4);
        uint4 o;
        o.x = pk2(v0.x, v0.y); o.y = pk2(v0.z, v0.w);
        o.z = pk2(v1.x, v1.y); o.w = pk2(v1.z, v1.w);
        *(uint4*)(wb + (long)i * 8) = o;
    }
}

// ---------- pass 2: bf16 GEMM, m97 structure ----------
constexpr int BM = 128, BN = 128, BK = 32;

__global__ __launch_bounds__(256) void mapper_gemm_bf(
    const unsigned short* __restrict__ xb,      // [b][s][d] bf16
    const int* __restrict__ lang_ids,
    const unsigned short* __restrict__ wb,      // [e][out][in] bf16
    const float* __restrict__ bias,
    const float* __restrict__ x,                // original, for pass-through
    float* __restrict__ out)
{
    // XCD-chunked bijective swizzle (4096 % 8 == 0): nt fastest -> the 8
    // blocks sharing an x-panel are consecutive on one XCD's L2.
    const int p  = blockIdx.x;
    const int l  = (p & 7) * 512 + (p >> 3);
    const int b  = l >> 7;
    const int mt = (l >> 3) & 15;
    const int nt = l & 7;
    const int s0 = mt * BM;
    const int e0 = nt * BN;
    const int tid = threadIdx.x;

    const int gid    = 8 - lang_ids[b];
    const bool active = (gid >= 1) && (gid <= 8);
    int eb = gid - 1; eb = eb < 0 ? 0 : (eb > 7 ? 7 : eb);

    if (!active) {
        const f32x4* xs = (const f32x4*)x;
        f32x4*       os = (f32x4*)out;
        const int rowstride4 = TBZ * TDIM / 4;
        for (int i = tid; i < (BM * BN) / 4; i += 256) {
            int r = i >> 5;
            int c = i & 31;
            long idx = (long)(s0 + r) * rowstride4 + b * (TDIM / 4) + (e0 >> 2) + c;
            os[idx] = xs[idx];
        }
        return;
    }

    __shared__ unsigned short As[BM * BK];   // 8 KB, linear [128][32]
    __shared__ unsigned short Bs[BN * BK];   // 8 KB

    const unsigned short* __restrict__ Aab = xb + (long)b  * TSEQ * TDIM + (long)s0 * TDIM;
    const unsigned short* __restrict__ Bbb = wb + (long)eb * TDIM * TDIM + (long)e0 * TDIM;

    const int lane = tid & 63;
    const int wave = tid >> 6;
    const int wr   = wave >> 1;
    const int wc   = wave & 1;
    const int fr   = lane & 15;
    const int fo   = (lane >> 4) * 8;

    // staging: thread t covers row (i*64 + (t>>2)), 16B at col (t&3)*8 bf16.
    // LDS dest == wave-uniform base + lane*16 (linear layout requirement).
    const int srow = tid >> 2;          // 0..63
    const int scol = (tid & 3) * 8;     // bf16 col

    f32x4 acc[4][4];
    #pragma unroll
    for (int m = 0; m < 4; ++m)
        #pragma unroll
        for (int n = 0; n < 4; ++n)
            acc[m][n] = (f32x4){0.f, 0.f, 0.f, 0.f};

    for (int k0 = 0; k0 < TDIM; k0 += BK) {
        __syncthreads();               // previous tile's readers done
        #pragma unroll
        for (int i = 0; i < 2; ++i) {
            const int r = i * 64 + srow;
            gload_lds16(Aab + (long)r * TDIM + k0 + scol, &As[r * BK + scol]);
            gload_lds16(Bbb + (long)r * TDIM + k0 + scol, &Bs[r * BK + scol]);
        }
        __syncthreads();               // compiler emits vmcnt(0) drain here

        bf16x8 af[4], bfm[4];
        #pragma unroll
        for (int m = 0; m < 4; ++m)
            af[m] = *(const bf16x8*)&As[(wr * 64 + m * 16 + fr) * BK + fo];
        #pragma unroll
        for (int n = 0; n < 4; ++n)
            bfm[n] = *(const bf16x8*)&Bs[(wc * 64 + n * 16 + fr) * BK + fo];
        #pragma unroll
        for (int m = 0; m < 4; ++m)
            #pragma unroll
            for (int n = 0; n < 4; ++n)
                acc[m][n] = __builtin_amdgcn_mfma_f32_16x16x32_bf16(af[m], bfm[n], acc[m][n], 0, 0, 0);
    }

    // epilogue: C/D col=lane&15, row=(lane>>4)*4+j  [verified round 1]
    const int cr = lane >> 4;
    const int cc = lane & 15;
    #pragma unroll
    for (int n = 0; n < 4; ++n) {
        const int e  = e0 + wc * 64 + n * 16 + cc;
        const float bv = bias[eb * TDIM + e];
        #pragma unroll
        for (int m = 0; m < 4; ++m) {
            #pragma unroll
            for (int j = 0; j < 4; ++j) {
                const int s = s0 + wr * 64 + m * 16 + cr * 4 + j;
                out[(long)s * (TBZ * TDIM) + b * TDIM + e] = acc[m][n][j] + bv;
            }
        }
    }
}

// ---------- fallback: round-1 fused kernel (419 us, passes) ----------
__device__ inline unsigned short f2bf(float f) {
    union { float f; unsigned int u; } v; v.f = f;
    unsigned int r = v.u + 0x7fffu + ((v.u >> 16) & 1u);
    return (unsigned short)(r >> 16);
}

constexpr int FLDS = 40;

__global__ __launch_bounds__(256) void mapper_fused(
    const float* __restrict__ x, const int* __restrict__ lang_ids,
    const float* __restrict__ W, const float* __restrict__ bias,
    float* __restrict__ out)
{
    const int bid = blockIdx.x;
    const int b   = bid >> 7;
    const int t   = bid & 127;
    const int mt  = t >> 3;
    const int nt  = t & 7;
    const int s0  = mt * BM;
    const int e0  = nt * BN;
    const int tid = threadIdx.x;

    const int gid    = 8 - lang_ids[b];
    const bool active = (gid >= 1) && (gid <= 8);
    int eb = gid - 1; eb = eb < 0 ? 0 : (eb > 7 ? 7 : eb);

    if (!active) {
        const f32x4* xs = (const f32x4*)x;
        f32x4*       os = (f32x4*)out;
        const int rowstride4 = TBZ * TDIM / 4;
        for (int i = tid; i < (BM * BN) / 4; i += 256) {
            int r = i >> 5, c = i & 31;
            long idx = (long)(s0 + r) * rowstride4 + b * (TDIM / 4) + (e0 >> 2) + c;
            os[idx] = xs[idx];
        }
        return;
    }

    __shared__ unsigned short As[BM * FLDS];
    __shared__ unsigned short Bs[BN * FLDS];
    const float* __restrict__ Wb = W + (long)eb * TDIM * TDIM;

    const int lane = tid & 63;
    const int wave = tid >> 6;
    const int wr   = wave >> 1;
    const int wc   = wave & 1;

    f32x4 acc[4][4];
    #pragma unroll
    for (int m = 0; m < 4; ++m)
        #pragma unroll
        for (int n = 0; n < 4; ++n)
            acc[m][n] = (f32x4){0.f, 0.f, 0.f, 0.f};

    const int rg = tid >> 3;
    const int cg = tid & 7;
    const int fr = lane & 15;
    const int fo = (lane >> 4) * 8;

    for (int k0 = 0; k0 < TDIM; k0 += 32) {
        __syncthreads();
        #pragma unroll
        for (int pp = 0; pp < 4; ++pp) {
            const int r = rg + pp * 32;
            f32x4 av = *(const f32x4*)(x  + (long)(s0 + r) * (TBZ * TDIM) + b * TDIM + k0 + cg * 4);
            f32x4 bv = *(const f32x4*)(Wb + (long)(e0 + r) * TDIM + k0 + cg * 4);
            unsigned int alo = (unsigned)f2bf(av.x) | ((unsigned)f2bf(av.y) << 16);
            unsigned int ahi = (unsigned)f2bf(av.z) | ((unsigned)f2bf(av.w) << 16);
            unsigned int blo = (unsigned)f2bf(bv.x) | ((unsigned)f2bf(bv.y) << 16);
            unsigned int bhi = (unsigned)f2bf(bv.z) | ((unsigned)f2bf(bv.w) << 16);
            *(uint2*)&As[r * FLDS + cg * 4] = make_uint2(alo, ahi);
            *(uint2*)&Bs[r * FLDS + cg * 4] = make_uint2(blo, bhi);
        }
        __syncthreads();

        bf16x8 af[4], bfm[4];
        #pragma unroll
        for (int m = 0; m < 4; ++m)
            af[m] = *(const bf16x8*)&As[(wr * 64 + m * 16 + fr) * FLDS + fo];
        #pragma unroll
        for (int n = 0; n < 4; ++n)
            bfm[n] = *(const bf16x8*)&Bs[(wc * 64 + n * 16 + fr) * FLDS + fo];
        #pragma unroll
        for (int m = 0; m < 4; ++m)
            #pragma unroll
            for (int n = 0; n < 4; ++n)
                acc[m][n] = __builtin_amdgcn_mfma_f32_16x16x32_bf16(af[m], bfm[n], acc[m][n], 0, 0, 0);
    }

    const int cr = lane >> 4;
    const int cc = lane & 15;
    #pragma unroll
    for (int n = 0; n < 4; ++n) {
        const int e  = e0 + wc * 64 + n * 16 + cc;
        const float bv = bias[eb * TDIM + e];
        #pragma unroll
        for (int m = 0; m < 4; ++m) {
            #pragma unroll
            for (int j = 0; j < 4; ++j) {
                const int s = s0 + wr * 64 + m * 16 + cr * 4 + j;
                out[(long)s * (TBZ * TDIM) + b * TDIM + e] = acc[m][n][j] + bv;
            }
        }
    }
}

extern "C" void kernel_launch(void* const* d_in, const int* in_sizes, int n_in,
                              void* d_out, int out_size, void* d_ws, size_t ws_size,
                              hipStream_t stream) {
    const float* x        = (const float*)d_in[0];
    const int*   lang_ids = (const int*)d_in[1];
    const float* W        = (const float*)d_in[2];
    const float* bias     = (const float*)d_in[3];
    float*       out      = (float*)d_out;

    const size_t xbytes = (size_t)TSEQ * TBZ * TDIM * 2;   // 128 MiB
    const size_t wbytes = (size_t)NLS * TDIM * TDIM * 2;   // 16 MiB
    const int grid = TBZ * (TSEQ / BM) * (TDIM / BN);      // 4096

    if (ws_size >= xbytes + wbytes) {
        unsigned short* xbp = (unsigned short*)d_ws;
        unsigned short* wbp = (unsigned short*)((char*)d_ws + xbytes);
        conv_x<<<4096, 256, 0, stream>>>(x, xbp);
        conv_w<<<2048, 256, 0, stream>>>(W, wbp);
        mapper_gemm_bf<<<grid, 256, 0, stream>>>(xbp, lang_ids, wbp, bias, x, out);
    } else {
        mapper_fused<<<grid, 256, 0, stream>>>(x, lang_ids, W, bias, out);
    }
}

// Round 4
// 272.368 us; speedup vs baseline: 2.0950x; 1.3449x over previous
//
#include <hip/hip_runtime.h>
#include <hip/hip_bf16.h>

#define TSEQ 2048
#define TBZ  32
#define TDIM 1024
#define NLS  8

typedef __attribute__((ext_vector_type(8))) short bf16x8;
typedef __attribute__((ext_vector_type(4))) float f32x4;

__device__ inline unsigned int pk2(float lo, float hi) {
    __hip_bfloat162 h = __float22bfloat162_rn(make_float2(lo, hi)); // v_cvt_pk_bf16_f32
    return *reinterpret_cast<const unsigned int*>(&h);
}

__device__ inline void gload_lds16(const void* g, void* l) {
    __builtin_amdgcn_global_load_lds(
        (const __attribute__((address_space(1))) unsigned int*)g,
        (__attribute__((address_space(3))) unsigned int*)l,
        16, 0, 0);
}

// ---------- pass 1a: x [s][b][d] f32 -> xb [b][s][d] bf16 ----------
__global__ __launch_bounds__(256) void conv_x(const float* __restrict__ x,
                                              unsigned short* __restrict__ xb) {
    const int total = TSEQ * TBZ * TDIM / 8;
    const int stride = gridDim.x * 256;
    for (int i = blockIdx.x * 256 + threadIdx.x; i < total; i += stride) {
        const int d8  = i & (TDIM / 8 - 1);
        const int row = i >> 7;
        const int s   = row >> 5;
        const int b   = row & (TBZ - 1);
        const float* src = x + (long)row * TDIM + d8 * 8;
        f32x4 v0 = *(const f32x4*)(src);
        f32x4 v1 = *(const f32x4*)(src + 4);
        uint4 o;
        o.x = pk2(v0.x, v0.y); o.y = pk2(v0.z, v0.w);
        o.z = pk2(v1.x, v1.y); o.w = pk2(v1.z, v1.w);
        *(uint4*)(xb + (long)(b * TSEQ + s) * TDIM + d8 * 8) = o;
    }
}

// ---------- pass 1b: W f32 -> bf16 ----------
__global__ __launch_bounds__(256) void conv_w(const float* __restrict__ W,
                                              unsigned short* __restrict__ wb) {
    const int total = NLS * TDIM * TDIM / 8;
    const int stride = gridDim.x * 256;
    for (int i = blockIdx.x * 256 + threadIdx.x; i < total; i += stride) {
        const float* src = W + (long)i * 8;
        f32x4 v0 = *(const f32x4*)(src);
        f32x4 v1 = *(const f32x4*)(src + 4);
        uint4 o;
        o.x = pk2(v0.x, v0.y); o.y = pk2(v0.z, v0.w);
        o.z = pk2(v1.x, v1.y); o.w = pk2(v1.z, v1.w);
        *(uint4*)(wb + (long)i * 8) = o;
    }
}

// ---------- pass 2: 256x256 8-phase bf16 GEMM ----------
// Tiles: BM=BN=256, BK=64. 8 waves (2M x 4N), per-wave out 128x64.
// LDS 128 KiB: A[2 slots][2 mh][128 rows][64 cols], B likewise. Half-tile =
// 16 KiB contiguous (mh region = union of both wr-waves' mh rows).
// Swizzle: 16B chunk c at region-row rr lives at chunk c^(rr&7); staging
// applies the inverse on the per-lane GLOBAL address (rule 21, m173).
// Schedule (per iter, tiles ta=2i slot0 / tb=2i+1 slot1):
//   P1 (t_a mh0,nh0) stage Amh1(tb)    P5 (t_b mh0,nh0) stage Amh1(ta+2)
//   P2 (t_a mh0,nh1) stage Amh0(ta+2)  P6 (t_b mh0,nh1) stage Amh0(tb+2)
//   P3 (t_a mh1,nh0) stage Bnh0(ta+2)  P7 (t_b mh1,nh0) stage Bnh0(tb+2)
//   P4 (t_a mh1,nh1) stage Bnh1(ta+2)  P8 (t_b mh1,nh1) stage Bnh1(tb+2)
// vmcnt(6) at end-P4/P8 only => all but 3 newest halves landed; every
// consumer's half was staged >=4 stages earlier (verified per-phase).

#define BAR __builtin_amdgcn_s_barrier()
#define LGKM asm volatile("s_waitcnt lgkmcnt(0)" ::: "memory")
#define VMC(n) asm volatile("s_waitcnt vmcnt(" #n ")" ::: "memory")

__global__ __launch_bounds__(512, 2) void mapper_gemm8(
    const unsigned short* __restrict__ xb,      // [b][s][d] bf16
    const int* __restrict__ lang_ids,
    const unsigned short* __restrict__ wb,      // [e][out][in] bf16
    const float* __restrict__ bias,
    const float* __restrict__ x,
    float* __restrict__ out)
{
    // XCD-chunked bijective swizzle: 1024 = 8 * 128.
    const int p  = blockIdx.x;
    const int l  = (p & 7) * 128 + (p >> 3);
    const int b  = l >> 5;
    const int mt = (l >> 2) & 7;
    const int nt = l & 3;
    const int s0 = mt * 256;
    const int e0 = nt * 256;
    const int tid = threadIdx.x;

    const int gid = 8 - lang_ids[b];
    const bool active = (gid >= 1) && (gid <= 8);
    int eb = gid - 1; eb = eb < 0 ? 0 : (eb > 7 ? 7 : eb);

    if (!active) {
        const f32x4* xs = (const f32x4*)x;
        f32x4*       os = (f32x4*)out;
        const int rs4 = TBZ * TDIM / 4;
        for (int i = tid; i < 256 * 256 / 4; i += 512) {
            int r = i >> 6;
            int c = i & 63;
            long idx = (long)(s0 + r) * rs4 + b * (TDIM / 4) + (e0 >> 2) + c;
            os[idx] = xs[idx];
        }
        return;
    }

    __shared__ uint4 ldsbuf[131072 / 16];
    char* ldsc = (char*)ldsbuf;

    const int lane = tid & 63;
    const int wave = tid >> 6;
    const int wr   = wave >> 2;     // 0..1
    const int wc   = wave & 3;      // 0..3
    const int fr   = lane & 15;
    const int fq   = lane >> 4;
    const int fr7  = fr & 7;

    const unsigned short* __restrict__ Aab = xb + (long)b  * TSEQ * TDIM + (long)s0 * TDIM;
    const unsigned short* __restrict__ Bbb = wb + (long)eb * TDIM * TDIM + (long)e0 * TDIM;

    // staging precompute: instr (wave,j) covers region-rows q*8..q*8+8, q=wave*2+j
    const int L    = lane;
    const int lch8 = ((L & 7) ^ (L >> 3)) * 8;   // pre-inverse-swizzled global chunk
    const int ldA0 = wave * 2048 + L * 16;        // region-local LDS byte offset (j=0)
    const unsigned short* aG[2][2];
    const unsigned short* bG[2][2];
    #pragma unroll
    for (int j = 0; j < 2; ++j) {
        const int rr = wave * 16 + j * 8 + (L >> 3);
        #pragma unroll
        for (int mh = 0; mh < 2; ++mh)
            aG[j][mh] = Aab + ((rr >> 6) * 128 + mh * 64 + (rr & 63)) * TDIM + lch8;
        #pragma unroll
        for (int nh = 0; nh < 2; ++nh)
            bG[j][nh] = Bbb + ((rr >> 5) * 64 + nh * 32 + (rr & 31)) * TDIM + lch8;
    }

#define STAGE_A(slot, mh, kofs) do { \
    gload_lds16(aG[0][mh] + (kofs), ldsc + (slot)*32768 + (mh)*16384 + ldA0); \
    gload_lds16(aG[1][mh] + (kofs), ldsc + (slot)*32768 + (mh)*16384 + ldA0 + 1024); \
} while (0)
#define STAGE_B(slot, nh, kofs) do { \
    gload_lds16(bG[0][nh] + (kofs), ldsc + 65536 + (slot)*32768 + (nh)*16384 + ldA0); \
    gload_lds16(bG[1][nh] + (kofs), ldsc + 65536 + (slot)*32768 + (nh)*16384 + ldA0 + 1024); \
} while (0)
#define RD_A(slot, mh) do { \
    _Pragma("unroll") for (int ml = 0; ml < 4; ++ml) { \
        const int rr = wr * 64 + ml * 16 + fr; \
        _Pragma("unroll") for (int kk = 0; kk < 2; ++kk) \
            af[ml][kk] = *(const bf16x8*)(ldsc + (slot)*32768 + (mh)*16384 + rr*128 + (((kk*4+fq) ^ fr7) << 4)); \
    } } while (0)
#define RD_B(slot, nh, br) do { \
    _Pragma("unroll") for (int nl = 0; nl < 2; ++nl) { \
        const int rr = wc * 32 + nl * 16 + fr; \
        _Pragma("unroll") for (int kk = 0; kk < 2; ++kk) \
            br[nl][kk] = *(const bf16x8*)(ldsc + 65536 + (slot)*32768 + (nh)*16384 + rr*128 + (((kk*4+fq) ^ fr7) << 4)); \
    } } while (0)
#define MM(mh, nh, br) do { \
    __builtin_amdgcn_s_setprio(1); \
    _Pragma("unroll") for (int ml = 0; ml < 4; ++ml) \
    _Pragma("unroll") for (int nl = 0; nl < 2; ++nl) \
    _Pragma("unroll") for (int kk = 0; kk < 2; ++kk) \
        acc[(mh)*4+ml][(nh)*2+nl] = __builtin_amdgcn_mfma_f32_16x16x32_bf16( \
            af[ml][kk], br[nl][kk], acc[(mh)*4+ml][(nh)*2+nl], 0, 0, 0); \
    __builtin_amdgcn_s_setprio(0); \
} while (0)

    f32x4 acc[8][4];
    #pragma unroll
    for (int m = 0; m < 8; ++m)
        #pragma unroll
        for (int n = 0; n < 4; ++n)
            acc[m][n] = (f32x4){0.f, 0.f, 0.f, 0.f};

    bf16x8 af[4][2], bf0[2][2], bf1[2][2];

    // prologue: tile0 all 4 halves + tile1 {Amh0,Bnh0,Bnh1}
    STAGE_A(0, 0, 0);  STAGE_B(0, 0, 0);  STAGE_B(0, 1, 0);  STAGE_A(0, 1, 0);
    STAGE_A(1, 0, 64); STAGE_B(1, 0, 64); STAGE_B(1, 1, 64);
    VMC(6); BAR;

    for (int it = 0; it < 7; ++it) {
        const int ka = it * 128;
        const int kb = ka + 64;    // tb
        const int kn = ka + 128;   // ta+2
        const int km = ka + 192;   // tb+2
        // P1
        RD_A(0, 0); RD_B(0, 0, bf0); STAGE_A(1, 1, kb);
        BAR; LGKM; MM(0, 0, bf0); BAR;
        // P2
        RD_B(0, 1, bf1); STAGE_A(0, 0, kn);
        BAR; LGKM; MM(0, 1, bf1); BAR;
        // P3
        RD_A(0, 1); STAGE_B(0, 0, kn);
        BAR; LGKM; MM(1, 0, bf0); BAR;
        // P4
        STAGE_B(0, 1, kn);
        BAR; MM(1, 1, bf1); VMC(6); BAR;
        // P5
        RD_A(1, 0); RD_B(1, 0, bf0); STAGE_A(0, 1, kn);
        BAR; LGKM; MM(0, 0, bf0); BAR;
        // P6
        RD_B(1, 1, bf1); STAGE_A(1, 0, km);
        BAR; LGKM; MM(0, 1, bf1); BAR;
        // P7
        RD_A(1, 1); STAGE_B(1, 0, km);
        BAR; LGKM; MM(1, 0, bf0); BAR;
        // P8
        STAGE_B(1, 1, km);
        BAR; MM(1, 1, bf1); VMC(6); BAR;
    }
    { // peeled last iteration (tiles 14,15): no future stages
        const int kb = 7 * 128 + 64;
        RD_A(0, 0); RD_B(0, 0, bf0); STAGE_A(1, 1, kb);
        BAR; LGKM; MM(0, 0, bf0); BAR;
        RD_B(0, 1, bf1);
        BAR; LGKM; MM(0, 1, bf1); BAR;
        RD_A(0, 1);
        BAR; LGKM; MM(1, 0, bf0); BAR;
        BAR; MM(1, 1, bf1); VMC(0); BAR;
        RD_A(1, 0); RD_B(1, 0, bf0);
        BAR; LGKM; MM(0, 0, bf0); BAR;
        RD_B(1, 1, bf1);
        BAR; LGKM; MM(0, 1, bf1); BAR;
        RD_A(1, 1);
        BAR; LGKM; MM(1, 0, bf0); BAR;
        BAR; MM(1, 1, bf1);
    }

    // epilogue: C/D col=lane&15, row=(lane>>4)*4+j [verified rounds 1-3]
    const int cr = lane >> 4;
    const int cc = lane & 15;
    #pragma unroll
    for (int n = 0; n < 4; ++n) {
        const int e  = e0 + wc * 64 + n * 16 + cc;
        const float bv = bias[eb * TDIM + e];
        #pragma unroll
        for (int m = 0; m < 8; ++m) {
            #pragma unroll
            for (int j = 0; j < 4; ++j) {
                const int s = s0 + wr * 128 + m * 16 + cr * 4 + j;
                out[(long)s * (TBZ * TDIM) + b * TDIM + e] = acc[m][n][j] + bv;
            }
        }
    }
#undef STAGE_A
#undef STAGE_B
#undef RD_A
#undef RD_B
#undef MM
}

// ---------- fallback: round-1 fused kernel ----------
__device__ inline unsigned short f2bf(float f) {
    union { float f; unsigned int u; } v; v.f = f;
    unsigned int r = v.u + 0x7fffu + ((v.u >> 16) & 1u);
    return (unsigned short)(r >> 16);
}
constexpr int FLDS = 40;

__global__ __launch_bounds__(256) void mapper_fused(
    const float* __restrict__ x, const int* __restrict__ lang_ids,
    const float* __restrict__ W, const float* __restrict__ bias,
    float* __restrict__ out)
{
    const int bid = blockIdx.x;
    const int b   = bid >> 7;
    const int t   = bid & 127;
    const int mt  = t >> 3;
    const int nt  = t & 7;
    const int s0  = mt * 128;
    const int e0  = nt * 128;
    const int tid = threadIdx.x;

    const int gid = 8 - lang_ids[b];
    const bool active = (gid >= 1) && (gid <= 8);
    int eb = gid - 1; eb = eb < 0 ? 0 : (eb > 7 ? 7 : eb);

    if (!active) {
        const f32x4* xs = (const f32x4*)x;
        f32x4*       os = (f32x4*)out;
        const int rs4 = TBZ * TDIM / 4;
        for (int i = tid; i < 128 * 128 / 4; i += 256) {
            int r = i >> 5, c = i & 31;
            long idx = (long)(s0 + r) * rs4 + b * (TDIM / 4) + (e0 >> 2) + c;
            os[idx] = xs[idx];
        }
        return;
    }

    __shared__ unsigned short As[128 * FLDS];
    __shared__ unsigned short Bs[128 * FLDS];
    const float* __restrict__ Wb = W + (long)eb * TDIM * TDIM;

    const int lane = tid & 63;
    const int wave = tid >> 6;
    const int wrr  = wave >> 1;
    const int wcc  = wave & 1;

    f32x4 acc[4][4];
    #pragma unroll
    for (int m = 0; m < 4; ++m)
        #pragma unroll
        for (int n = 0; n < 4; ++n)
            acc[m][n] = (f32x4){0.f, 0.f, 0.f, 0.f};

    const int rg = tid >> 3;
    const int cg = tid & 7;
    const int fr = lane & 15;
    const int fo = (lane >> 4) * 8;

    for (int k0 = 0; k0 < TDIM; k0 += 32) {
        __syncthreads();
        #pragma unroll
        for (int pp = 0; pp < 4; ++pp) {
            const int r = rg + pp * 32;
            f32x4 av = *(const f32x4*)(x  + (long)(s0 + r) * (TBZ * TDIM) + b * TDIM + k0 + cg * 4);
            f32x4 bv = *(const f32x4*)(Wb + (long)(e0 + r) * TDIM + k0 + cg * 4);
            unsigned int alo = (unsigned)f2bf(av.x) | ((unsigned)f2bf(av.y) << 16);
            unsigned int ahi = (unsigned)f2bf(av.z) | ((unsigned)f2bf(av.w) << 16);
            unsigned int blo = (unsigned)f2bf(bv.x) | ((unsigned)f2bf(bv.y) << 16);
            unsigned int bhi = (unsigned)f2bf(bv.z) | ((unsigned)f2bf(bv.w) << 16);
            *(uint2*)&As[r * FLDS + cg * 4] = make_uint2(alo, ahi);
            *(uint2*)&Bs[r * FLDS + cg * 4] = make_uint2(blo, bhi);
        }
        __syncthreads();

        bf16x8 af2[4], bfm[4];
        #pragma unroll
        for (int m = 0; m < 4; ++m)
            af2[m] = *(const bf16x8*)&As[(wrr * 64 + m * 16 + fr) * FLDS + fo];
        #pragma unroll
        for (int n = 0; n < 4; ++n)
            bfm[n] = *(const bf16x8*)&Bs[(wcc * 64 + n * 16 + fr) * FLDS + fo];
        #pragma unroll
        for (int m = 0; m < 4; ++m)
            #pragma unroll
            for (int n = 0; n < 4; ++n)
                acc[m][n] = __builtin_amdgcn_mfma_f32_16x16x32_bf16(af2[m], bfm[n], acc[m][n], 0, 0, 0);
    }

    const int cr = lane >> 4;
    const int cc = lane & 15;
    #pragma unroll
    for (int n = 0; n < 4; ++n) {
        const int e  = e0 + wcc * 64 + n * 16 + cc;
        const float bv = bias[eb * TDIM + e];
        #pragma unroll
        for (int m = 0; m < 4; ++m) {
            #pragma unroll
            for (int j = 0; j < 4; ++j) {
                const int s = s0 + wrr * 64 + m * 16 + cr * 4 + j;
                out[(long)s * (TBZ * TDIM) + b * TDIM + e] = acc[m][n][j] + bv;
            }
        }
    }
}

extern "C" void kernel_launch(void* const* d_in, const int* in_sizes, int n_in,
                              void* d_out, int out_size, void* d_ws, size_t ws_size,
                              hipStream_t stream) {
    const float* x        = (const float*)d_in[0];
    const int*   lang_ids = (const int*)d_in[1];
    const float* W        = (const float*)d_in[2];
    const float* bias     = (const float*)d_in[3];
    float*       out      = (float*)d_out;

    const size_t xbytes = (size_t)TSEQ * TBZ * TDIM * 2;   // 128 MiB
    const size_t wbytes = (size_t)NLS * TDIM * TDIM * 2;   // 16 MiB

    if (ws_size >= xbytes + wbytes) {
        unsigned short* xbp = (unsigned short*)d_ws;
        unsigned short* wbp = (unsigned short*)((char*)d_ws + xbytes);
        conv_x<<<4096, 256, 0, stream>>>(x, xbp);
        conv_w<<<2048, 256, 0, stream>>>(W, wbp);
        mapper_gemm8<<<TBZ * 8 * 4, 512, 0, stream>>>(xbp, lang_ids, wbp, bias, x, out);
    } else {
        mapper_fused<<<TBZ * 16 * 8, 256, 0, stream>>>(x, lang_ids, W, bias, out);
    }
}

// Round 5
// 271.376 us; speedup vs baseline: 2.1027x; 1.0037x over previous
//
#include <hip/hip_runtime.h>
#include <hip/hip_bf16.h>

#define TSEQ 2048
#define TBZ  32
#define TDIM 1024
#define NLS  8

typedef __attribute__((ext_vector_type(8))) short bf16x8;
typedef __attribute__((ext_vector_type(4))) float f32x4;

__device__ inline unsigned int pk2(float lo, float hi) {
    __hip_bfloat162 h = __float22bfloat162_rn(make_float2(lo, hi)); // v_cvt_pk_bf16_f32
    return *reinterpret_cast<const unsigned int*>(&h);
}

__device__ inline void gload_lds16(const void* g, void* l) {
    __builtin_amdgcn_global_load_lds(
        (const __attribute__((address_space(1))) unsigned int*)g,
        (__attribute__((address_space(3))) unsigned int*)l,
        16, 0, 0);
}

// ---------- pass 1: W->bf16, x->bf16 [b][s][d], inactive-col passthrough ----------
__global__ __launch_bounds__(256) void conv_all(
    const float* __restrict__ x, const int* __restrict__ lang_ids,
    const float* __restrict__ W,
    unsigned short* __restrict__ xb, unsigned short* __restrict__ wb,
    float* __restrict__ out)
{
    const int bid = blockIdx.x;
    if (bid < 512) {                               // W part: 1M chunks of 8
        const int total = NLS * TDIM * TDIM / 8;
        const int stride = 512 * 256;
        for (int i = bid * 256 + threadIdx.x; i < total; i += stride) {
            const float* src = W + (long)i * 8;
            f32x4 v0 = *(const f32x4*)(src);
            f32x4 v1 = *(const f32x4*)(src + 4);
            uint4 o;
            o.x = pk2(v0.x, v0.y); o.y = pk2(v0.z, v0.w);
            o.z = pk2(v1.x, v1.y); o.w = pk2(v1.z, v1.w);
            *(uint4*)(wb + (long)i * 8) = o;
        }
        return;
    }
    const int xbid = bid - 512;                    // x part: 8M chunks of 8
    const int total = TSEQ * TBZ * TDIM / 8;
    const int stride = 4096 * 256;
    for (int i = xbid * 256 + threadIdx.x; i < total; i += stride) {
        const int d8  = i & (TDIM / 8 - 1);
        const int row = i >> 7;                    // s*TBZ + b
        const int b   = row & (TBZ - 1);
        const int gid = 8 - lang_ids[b];
        const float* src = x + (long)row * TDIM + d8 * 8;
        f32x4 v0 = *(const f32x4*)(src);
        f32x4 v1 = *(const f32x4*)(src + 4);
        if (gid >= 1 && gid <= 8) {
            const int s = row >> 5;
            uint4 o;
            o.x = pk2(v0.x, v0.y); o.y = pk2(v0.z, v0.w);
            o.z = pk2(v1.x, v1.y); o.w = pk2(v1.z, v1.w);
            *(uint4*)(xb + (long)(b * TSEQ + s) * TDIM + d8 * 8) = o;
        } else {                                   // passthrough: out = x
            float* dst = out + (long)row * TDIM + d8 * 8;
            *(f32x4*)(dst)     = v0;
            *(f32x4*)(dst + 4) = v1;
        }
    }
}

// ---------- pass 2: persistent 256x256 8-phase bf16 GEMM, 2 m-tiles/block ----------
// Same verified schedule/swizzle as round 4. Uniform 8-iteration K-loop per
// m-tile: stage k-offsets kn=ka+128, km=ka+192 wrap into the NEXT m-tile's A
// panel via kofs = (kv&1023) + (kv>>10)*262144 (B wraps to k=0, same panel),
// so iteration 8's stage slots ARE the next tile's prologue. Epilogue sits
// between bridge and next P1: stores drain under prefetched halves. vmcnt is
// in-order, so interposed stores only strengthen the VMC(6) guarantee.

#define BAR __builtin_amdgcn_s_barrier()
#define LGKM asm volatile("s_waitcnt lgkmcnt(0)" ::: "memory")
#define VMC(n) asm volatile("s_waitcnt vmcnt(" #n ")" ::: "memory")
#define KAo(kv) (((kv) & 1023) + (((kv) >> 10) << 18))
#define KBo(kv) ((kv) & 1023)

__global__ __launch_bounds__(512, 2) void mapper_gemm8p(
    const unsigned short* __restrict__ xb,      // [b][s][d] bf16
    const int* __restrict__ lang_ids,
    const unsigned short* __restrict__ wb,      // [e][out][in] bf16
    const float* __restrict__ bias,
    float* __restrict__ out)
{
    // XCD-chunked bijective swizzle: 512 = 8 * 64; nt fastest so the 4
    // blocks sharing an A strip-panel are consecutive on one XCD.
    const int p  = blockIdx.x;
    const int l  = (p & 7) * 64 + (p >> 3);
    const int b  = l >> 4;
    const int strip = (l >> 2) & 3;             // 2 m-tiles per strip
    const int nt = l & 3;
    const int s0 = strip * 512;
    const int e0 = nt * 256;
    const int tid = threadIdx.x;

    const int gid = 8 - lang_ids[b];
    if (!(gid >= 1 && gid <= 8)) return;        // conv_all wrote passthrough
    const int eb = gid - 1;

    __shared__ uint4 ldsbuf[131072 / 16];
    char* ldsc = (char*)ldsbuf;

    const int lane = tid & 63;
    const int wave = tid >> 6;
    const int wr   = wave >> 2;
    const int wc   = wave & 3;
    const int fr   = lane & 15;
    const int fq   = lane >> 4;
    const int fr7  = fr & 7;

    const unsigned short* __restrict__ Aab = xb + (long)b  * TSEQ * TDIM + (long)s0 * TDIM;
    const unsigned short* __restrict__ Bbb = wb + (long)eb * TDIM * TDIM + (long)e0 * TDIM;

    const int L    = lane;
    const int lch8 = ((L & 7) ^ (L >> 3)) * 8;   // pre-inverse-swizzled global chunk
    const int ldA0 = wave * 2048 + L * 16;
    const unsigned short* aG[2][2];
    const unsigned short* bG[2][2];
    #pragma unroll
    for (int j = 0; j < 2; ++j) {
        const int rr = wave * 16 + j * 8 + (L >> 3);
        #pragma unroll
        for (int mh = 0; mh < 2; ++mh)
            aG[j][mh] = Aab + ((rr >> 6) * 128 + mh * 64 + (rr & 63)) * TDIM + lch8;
        #pragma unroll
        for (int nh = 0; nh < 2; ++nh)
            bG[j][nh] = Bbb + ((rr >> 5) * 64 + nh * 32 + (rr & 31)) * TDIM + lch8;
    }

#define STAGE_A(slot, mh, kofs) do { \
    gload_lds16(aG[0][mh] + (kofs), ldsc + (slot)*32768 + (mh)*16384 + ldA0); \
    gload_lds16(aG[1][mh] + (kofs), ldsc + (slot)*32768 + (mh)*16384 + ldA0 + 1024); \
} while (0)
#define STAGE_B(slot, nh, kofs) do { \
    gload_lds16(bG[0][nh] + (kofs), ldsc + 65536 + (slot)*32768 + (nh)*16384 + ldA0); \
    gload_lds16(bG[1][nh] + (kofs), ldsc + 65536 + (slot)*32768 + (nh)*16384 + ldA0 + 1024); \
} while (0)
#define RD_A(slot, mh) do { \
    _Pragma("unroll") for (int ml = 0; ml < 4; ++ml) { \
        const int rr = wr * 64 + ml * 16 + fr; \
        _Pragma("unroll") for (int kk = 0; kk < 2; ++kk) \
            af[ml][kk] = *(const bf16x8*)(ldsc + (slot)*32768 + (mh)*16384 + rr*128 + (((kk*4+fq) ^ fr7) << 4)); \
    } } while (0)
#define RD_B(slot, nh, br) do { \
    _Pragma("unroll") for (int nl = 0; nl < 2; ++nl) { \
        const int rr = wc * 32 + nl * 16 + fr; \
        _Pragma("unroll") for (int kk = 0; kk < 2; ++kk) \
            br[nl][kk] = *(const bf16x8*)(ldsc + 65536 + (slot)*32768 + (nh)*16384 + rr*128 + (((kk*4+fq) ^ fr7) << 4)); \
    } } while (0)
#define MM(mh, nh, br) do { \
    __builtin_amdgcn_s_setprio(1); \
    _Pragma("unroll") for (int ml = 0; ml < 4; ++ml) \
    _Pragma("unroll") for (int nl = 0; nl < 2; ++nl) \
    _Pragma("unroll") for (int kk = 0; kk < 2; ++kk) \
        acc[(mh)*4+ml][(nh)*2+nl] = __builtin_amdgcn_mfma_f32_16x16x32_bf16( \
            af[ml][kk], br[nl][kk], acc[(mh)*4+ml][(nh)*2+nl], 0, 0, 0); \
    __builtin_amdgcn_s_setprio(0); \
} while (0)

    f32x4 acc[8][4];
    #pragma unroll
    for (int m = 0; m < 8; ++m)
        #pragma unroll
        for (int n = 0; n < 4; ++n)
            acc[m][n] = (f32x4){0.f, 0.f, 0.f, 0.f};

    bf16x8 af[4][2], bf0[2][2], bf1[2][2];

    // prologue: tile0 all 4 halves + tile1 {Amh0,Bnh0,Bnh1}
    STAGE_A(0, 0, 0);  STAGE_B(0, 0, 0);  STAGE_B(0, 1, 0);  STAGE_A(0, 1, 0);
    STAGE_A(1, 0, 64); STAGE_B(1, 0, 64); STAGE_B(1, 1, 64);
    VMC(6); BAR;

    const int cr = lane >> 4;
    const int cc = lane & 15;

    for (int mtl = 0; mtl < 2; ++mtl) {
        for (int it = 0; it < 8; ++it) {
            const int kva = mtl * 1024 + it * 128;
            const int kb = kva + 64;
            const int kn = kva + 128;   // wraps to next m-tile after it=7
            const int km = kva + 192;
            // P1
            RD_A(0, 0); RD_B(0, 0, bf0); STAGE_A(1, 1, KAo(kb));
            BAR; LGKM; MM(0, 0, bf0); BAR;
            // P2
            RD_B(0, 1, bf1); STAGE_A(0, 0, KAo(kn));
            BAR; LGKM; MM(0, 1, bf1); BAR;
            // P3
            RD_A(0, 1); STAGE_B(0, 0, KBo(kn));
            BAR; LGKM; MM(1, 0, bf0); BAR;
            // P4
            STAGE_B(0, 1, KBo(kn));
            BAR; MM(1, 1, bf1); VMC(6); BAR;
            // P5
            RD_A(1, 0); RD_B(1, 0, bf0); STAGE_A(0, 1, KAo(kn));
            BAR; LGKM; MM(0, 0, bf0); BAR;
            // P6
            RD_B(1, 1, bf1); STAGE_A(1, 0, KAo(km));
            BAR; LGKM; MM(0, 1, bf1); BAR;
            // P7
            RD_A(1, 1); STAGE_B(1, 0, KBo(km));
            BAR; LGKM; MM(1, 0, bf0); BAR;
            // P8
            STAGE_B(1, 1, KBo(km));
            BAR; MM(1, 1, bf1); VMC(6); BAR;
        }

        // epilogue for this m-tile; stores drain under the bridge prefetch
        const int sb = s0 + mtl * 256 + wr * 128;
        #pragma unroll
        for (int n = 0; n < 4; ++n) {
            const int e  = e0 + wc * 64 + n * 16 + cc;
            const float bv = bias[eb * TDIM + e];
            #pragma unroll
            for (int m = 0; m < 8; ++m) {
                #pragma unroll
                for (int j = 0; j < 4; ++j) {
                    const int s = sb + m * 16 + cr * 4 + j;
                    out[(long)s * (TBZ * TDIM) + b * TDIM + e] = acc[m][n][j] + bv;
                }
            }
        }
        #pragma unroll
        for (int m = 0; m < 8; ++m)
            #pragma unroll
            for (int n = 0; n < 4; ++n)
                acc[m][n] = (f32x4){0.f, 0.f, 0.f, 0.f};
    }
#undef STAGE_A
#undef STAGE_B
#undef RD_A
#undef RD_B
#undef MM
}

// ---------- fallback: round-1 fused kernel ----------
__device__ inline unsigned short f2bf(float f) {
    union { float f; unsigned int u; } v; v.f = f;
    unsigned int r = v.u + 0x7fffu + ((v.u >> 16) & 1u);
    return (unsigned short)(r >> 16);
}
constexpr int FLDS = 40;

__global__ __launch_bounds__(256) void mapper_fused(
    const float* __restrict__ x, const int* __restrict__ lang_ids,
    const float* __restrict__ W, const float* __restrict__ bias,
    float* __restrict__ out)
{
    const int bid = blockIdx.x;
    const int b   = bid >> 7;
    const int t   = bid & 127;
    const int mt  = t >> 3;
    const int nt  = t & 7;
    const int s0  = mt * 128;
    const int e0  = nt * 128;
    const int tid = threadIdx.x;

    const int gid = 8 - lang_ids[b];
    const bool active = (gid >= 1) && (gid <= 8);
    int eb = gid - 1; eb = eb < 0 ? 0 : (eb > 7 ? 7 : eb);

    if (!active) {
        const f32x4* xs = (const f32x4*)x;
        f32x4*       os = (f32x4*)out;
        const int rs4 = TBZ * TDIM / 4;
        for (int i = tid; i < 128 * 128 / 4; i += 256) {
            int r = i >> 5, c = i & 31;
            long idx = (long)(s0 + r) * rs4 + b * (TDIM / 4) + (e0 >> 2) + c;
            os[idx] = xs[idx];
        }
        return;
    }

    __shared__ unsigned short As[128 * FLDS];
    __shared__ unsigned short Bs[128 * FLDS];
    const float* __restrict__ Wb = W + (long)eb * TDIM * TDIM;

    const int lane = tid & 63;
    const int wave = tid >> 6;
    const int wrr  = wave >> 1;
    const int wcc  = wave & 1;

    f32x4 acc[4][4];
    #pragma unroll
    for (int m = 0; m < 4; ++m)
        #pragma unroll
        for (int n = 0; n < 4; ++n)
            acc[m][n] = (f32x4){0.f, 0.f, 0.f, 0.f};

    const int rg = tid >> 3;
    const int cg = tid & 7;
    const int fr = lane & 15;
    const int fo = (lane >> 4) * 8;

    for (int k0 = 0; k0 < TDIM; k0 += 32) {
        __syncthreads();
        #pragma unroll
        for (int pp = 0; pp < 4; ++pp) {
            const int r = rg + pp * 32;
            f32x4 av = *(const f32x4*)(x  + (long)(s0 + r) * (TBZ * TDIM) + b * TDIM + k0 + cg * 4);
            f32x4 bv = *(const f32x4*)(Wb + (long)(e0 + r) * TDIM + k0 + cg * 4);
            unsigned int alo = (unsigned)f2bf(av.x) | ((unsigned)f2bf(av.y) << 16);
            unsigned int ahi = (unsigned)f2bf(av.z) | ((unsigned)f2bf(av.w) << 16);
            unsigned int blo = (unsigned)f2bf(bv.x) | ((unsigned)f2bf(bv.y) << 16);
            unsigned int bhi = (unsigned)f2bf(bv.z) | ((unsigned)f2bf(bv.w) << 16);
            *(uint2*)&As[r * FLDS + cg * 4] = make_uint2(alo, ahi);
            *(uint2*)&Bs[r * FLDS + cg * 4] = make_uint2(blo, bhi);
        }
        __syncthreads();

        bf16x8 af2[4], bfm[4];
        #pragma unroll
        for (int m = 0; m < 4; ++m)
            af2[m] = *(const bf16x8*)&As[(wrr * 64 + m * 16 + fr) * FLDS + fo];
        #pragma unroll
        for (int n = 0; n < 4; ++n)
            bfm[n] = *(const bf16x8*)&Bs[(wcc * 64 + n * 16 + fr) * FLDS + fo];
        #pragma unroll
        for (int m = 0; m < 4; ++m)
            #pragma unroll
            for (int n = 0; n < 4; ++n)
                acc[m][n] = __builtin_amdgcn_mfma_f32_16x16x32_bf16(af2[m], bfm[n], acc[m][n], 0, 0, 0);
    }

    const int cr = lane >> 4;
    const int cc = lane & 15;
    #pragma unroll
    for (int n = 0; n < 4; ++n) {
        const int e  = e0 + wcc * 64 + n * 16 + cc;
        const float bv = bias[eb * TDIM + e];
        #pragma unroll
        for (int m = 0; m < 4; ++m) {
            #pragma unroll
            for (int j = 0; j < 4; ++j) {
                const int s = s0 + wrr * 64 + m * 16 + cr * 4 + j;
                out[(long)s * (TBZ * TDIM) + b * TDIM + e] = acc[m][n][j] + bv;
            }
        }
    }
}

extern "C" void kernel_launch(void* const* d_in, const int* in_sizes, int n_in,
                              void* d_out, int out_size, void* d_ws, size_t ws_size,
                              hipStream_t stream) {
    const float* x        = (const float*)d_in[0];
    const int*   lang_ids = (const int*)d_in[1];
    const float* W        = (const float*)d_in[2];
    const float* bias     = (const float*)d_in[3];
    float*       out      = (float*)d_out;

    const size_t xbytes = (size_t)TSEQ * TBZ * TDIM * 2;   // 128 MiB
    const size_t wbytes = (size_t)NLS * TDIM * TDIM * 2;   // 16 MiB

    if (ws_size >= xbytes + wbytes) {
        unsigned short* xbp = (unsigned short*)d_ws;
        unsigned short* wbp = (unsigned short*)((char*)d_ws + xbytes);
        conv_all<<<4608, 256, 0, stream>>>(x, lang_ids, W, xbp, wbp, out);
        mapper_gemm8p<<<512, 512, 0, stream>>>(xbp, lang_ids, wbp, bias, out);
    } else {
        mapper_fused<<<TBZ * 16 * 8, 256, 0, stream>>>(x, lang_ids, W, bias, out);
    }
}

// Round 6
// 260.397 us; speedup vs baseline: 2.1913x; 1.0422x over previous
//
#include <hip/hip_runtime.h>
#include <hip/hip_bf16.h>

#define TSEQ 2048
#define TBZ  32
#define TDIM 1024
#define NLS  8

typedef __attribute__((ext_vector_type(8))) short bf16x8;
typedef __attribute__((ext_vector_type(4))) float f32x4;

__device__ inline unsigned int pk2(float lo, float hi) {
    __hip_bfloat162 h = __float22bfloat162_rn(make_float2(lo, hi)); // v_cvt_pk_bf16_f32
    return *reinterpret_cast<const unsigned int*>(&h);
}

__device__ inline void gload_lds16(const void* g, void* l) {
    __builtin_amdgcn_global_load_lds(
        (const __attribute__((address_space(1))) unsigned int*)g,
        (__attribute__((address_space(3))) unsigned int*)l,
        16, 0, 0);
}

// ---------- pass 1a: x [s][b][d] f32 -> xb [b][s][d] bf16 (all columns) ----------
__global__ __launch_bounds__(256) void conv_x(const float* __restrict__ x,
                                              unsigned short* __restrict__ xb) {
    const int total = TSEQ * TBZ * TDIM / 8;
    const int stride = gridDim.x * 256;
    for (int i = blockIdx.x * 256 + threadIdx.x; i < total; i += stride) {
        const int d8  = i & (TDIM / 8 - 1);
        const int row = i >> 7;                    // s*TBZ + b
        const int s   = row >> 5;
        const int b   = row & (TBZ - 1);
        const float* src = x + (long)row * TDIM + d8 * 8;
        f32x4 v0 = *(const f32x4*)(src);
        f32x4 v1 = *(const f32x4*)(src + 4);
        uint4 o;
        o.x = pk2(v0.x, v0.y); o.y = pk2(v0.z, v0.w);
        o.z = pk2(v1.x, v1.y); o.w = pk2(v1.z, v1.w);
        *(uint4*)(xb + (long)(b * TSEQ + s) * TDIM + d8 * 8) = o;
    }
}

// ---------- pass 1b: W f32 -> bf16 ----------
__global__ __launch_bounds__(256) void conv_w(const float* __restrict__ W,
                                              unsigned short* __restrict__ wb) {
    const int total = NLS * TDIM * TDIM / 8;
    const int stride = gridDim.x * 256;
    for (int i = blockIdx.x * 256 + threadIdx.x; i < total; i += stride) {
        const float* src = W + (long)i * 8;
        f32x4 v0 = *(const f32x4*)(src);
        f32x4 v1 = *(const f32x4*)(src + 4);
        uint4 o;
        o.x = pk2(v0.x, v0.y); o.y = pk2(v0.z, v0.w);
        o.z = pk2(v1.x, v1.y); o.w = pk2(v1.z, v1.w);
        *(uint4*)(wb + (long)i * 8) = o;
    }
}

// ---------- pass 2: persistent 256x256 8-phase bf16 GEMM, 2 m-tiles/block ----------
// Schedule/swizzle identical to rounds 4/5 (verified). Change: MFMA operands
// swapped -> each fragment is C^T: lane holds col=lane&15 = s_local, and
// row=(lane>>4)*4+j = 4 CONSECUTIVE e -> epilogue is 32 global_store_dwordx4
// (was 128 scalar stores). Fewer vmcnt queue entries + full 64B segments =>
// the bridge's VMC(6) drains the epilogue much faster.

#define BAR __builtin_amdgcn_s_barrier()
#define LGKM asm volatile("s_waitcnt lgkmcnt(0)" ::: "memory")
#define VMC(n) asm volatile("s_waitcnt vmcnt(" #n ")" ::: "memory")
#define KAo(kv) (((kv) & 1023) + (((kv) >> 10) << 18))
#define KBo(kv) ((kv) & 1023)

__global__ __launch_bounds__(512, 2) void mapper_gemm8p(
    const unsigned short* __restrict__ xb,      // [b][s][d] bf16
    const int* __restrict__ lang_ids,
    const unsigned short* __restrict__ wb,      // [e][out][in] bf16
    const float* __restrict__ bias,
    const float* __restrict__ x,                // original, for passthrough
    float* __restrict__ out)
{
    // XCD-chunked bijective swizzle: 512 = 8 * 64; nt fastest so the 4
    // blocks sharing an A strip-panel are consecutive on one XCD.
    const int p  = blockIdx.x;
    const int l  = (p & 7) * 64 + (p >> 3);
    const int b  = l >> 4;
    const int strip = (l >> 2) & 3;             // 2 m-tiles per strip
    const int nt = l & 3;
    const int s0 = strip * 512;
    const int e0 = nt * 256;
    const int tid = threadIdx.x;

    const int gid = 8 - lang_ids[b];
    if (!(gid >= 1 && gid <= 8)) {
        // passthrough: out[s0..s0+512][b][e0..e0+256] = x[...]
        const f32x4* xs = (const f32x4*)x;
        f32x4*       os = (f32x4*)out;
        const int rs4 = TBZ * TDIM / 4;
        for (int i = tid; i < 512 * 256 / 4; i += 512) {
            int r = i >> 6;
            int c = i & 63;
            long idx = (long)(s0 + r) * rs4 + b * (TDIM / 4) + (e0 >> 2) + c;
            os[idx] = xs[idx];
        }
        return;
    }
    const int eb = gid - 1;

    __shared__ uint4 ldsbuf[131072 / 16];
    char* ldsc = (char*)ldsbuf;

    const int lane = tid & 63;
    const int wave = tid >> 6;
    const int wr   = wave >> 2;
    const int wc   = wave & 3;
    const int fr   = lane & 15;
    const int fq   = lane >> 4;
    const int fr7  = fr & 7;

    const unsigned short* __restrict__ Aab = xb + (long)b  * TSEQ * TDIM + (long)s0 * TDIM;
    const unsigned short* __restrict__ Bbb = wb + (long)eb * TDIM * TDIM + (long)e0 * TDIM;

    const int L    = lane;
    const int lch8 = ((L & 7) ^ (L >> 3)) * 8;   // pre-inverse-swizzled global chunk
    const int ldA0 = wave * 2048 + L * 16;
    const unsigned short* aG[2][2];
    const unsigned short* bG[2][2];
    #pragma unroll
    for (int j = 0; j < 2; ++j) {
        const int rr = wave * 16 + j * 8 + (L >> 3);
        #pragma unroll
        for (int mh = 0; mh < 2; ++mh)
            aG[j][mh] = Aab + ((rr >> 6) * 128 + mh * 64 + (rr & 63)) * TDIM + lch8;
        #pragma unroll
        for (int nh = 0; nh < 2; ++nh)
            bG[j][nh] = Bbb + ((rr >> 5) * 64 + nh * 32 + (rr & 31)) * TDIM + lch8;
    }

#define STAGE_A(slot, mh, kofs) do { \
    gload_lds16(aG[0][mh] + (kofs), ldsc + (slot)*32768 + (mh)*16384 + ldA0); \
    gload_lds16(aG[1][mh] + (kofs), ldsc + (slot)*32768 + (mh)*16384 + ldA0 + 1024); \
} while (0)
#define STAGE_B(slot, nh, kofs) do { \
    gload_lds16(bG[0][nh] + (kofs), ldsc + 65536 + (slot)*32768 + (nh)*16384 + ldA0); \
    gload_lds16(bG[1][nh] + (kofs), ldsc + 65536 + (slot)*32768 + (nh)*16384 + ldA0 + 1024); \
} while (0)
#define RD_A(slot, mh) do { \
    _Pragma("unroll") for (int ml = 0; ml < 4; ++ml) { \
        const int rr = wr * 64 + ml * 16 + fr; \
        _Pragma("unroll") for (int kk = 0; kk < 2; ++kk) \
            af[ml][kk] = *(const bf16x8*)(ldsc + (slot)*32768 + (mh)*16384 + rr*128 + (((kk*4+fq) ^ fr7) << 4)); \
    } } while (0)
#define RD_B(slot, nh, br) do { \
    _Pragma("unroll") for (int nl = 0; nl < 2; ++nl) { \
        const int rr = wc * 32 + nl * 16 + fr; \
        _Pragma("unroll") for (int kk = 0; kk < 2; ++kk) \
            br[nl][kk] = *(const bf16x8*)(ldsc + 65536 + (slot)*32768 + (nh)*16384 + rr*128 + (((kk*4+fq) ^ fr7) << 4)); \
    } } while (0)
// Swapped operands: D = B-frag x A-frag = C^T. Within each 16x16 fragment:
// col=lane&15 -> s_local, row=(lane>>4)*4+j -> e_local (4 consecutive e).
#define MM(mh, nh, br) do { \
    __builtin_amdgcn_s_setprio(1); \
    _Pragma("unroll") for (int ml = 0; ml < 4; ++ml) \
    _Pragma("unroll") for (int nl = 0; nl < 2; ++nl) \
    _Pragma("unroll") for (int kk = 0; kk < 2; ++kk) \
        acc[(mh)*4+ml][(nh)*2+nl] = __builtin_amdgcn_mfma_f32_16x16x32_bf16( \
            br[nl][kk], af[ml][kk], acc[(mh)*4+ml][(nh)*2+nl], 0, 0, 0); \
    __builtin_amdgcn_s_setprio(0); \
} while (0)

    f32x4 acc[8][4];
    #pragma unroll
    for (int m = 0; m < 8; ++m)
        #pragma unroll
        for (int n = 0; n < 4; ++n)
            acc[m][n] = (f32x4){0.f, 0.f, 0.f, 0.f};

    bf16x8 af[4][2], bf0[2][2], bf1[2][2];

    // prologue: tile0 all 4 halves + tile1 {Amh0,Bnh0,Bnh1}
    STAGE_A(0, 0, 0);  STAGE_B(0, 0, 0);  STAGE_B(0, 1, 0);  STAGE_A(0, 1, 0);
    STAGE_A(1, 0, 64); STAGE_B(1, 0, 64); STAGE_B(1, 1, 64);
    VMC(6); BAR;

    const int cs  = lane & 15;          // s_local
    const int eqb = (lane >> 4) << 2;   // e_local base (4 consecutive)

    for (int mtl = 0; mtl < 2; ++mtl) {
        for (int it = 0; it < 8; ++it) {
            const int kva = mtl * 1024 + it * 128;
            const int kb = kva + 64;
            const int kn = kva + 128;   // wraps into next m-tile after it=7
            const int km = kva + 192;
            // P1
            RD_A(0, 0); RD_B(0, 0, bf0); STAGE_A(1, 1, KAo(kb));
            BAR; LGKM; MM(0, 0, bf0); BAR;
            // P2
            RD_B(0, 1, bf1); STAGE_A(0, 0, KAo(kn));
            BAR; LGKM; MM(0, 1, bf1); BAR;
            // P3
            RD_A(0, 1); STAGE_B(0, 0, KBo(kn));
            BAR; LGKM; MM(1, 0, bf0); BAR;
            // P4
            STAGE_B(0, 1, KBo(kn));
            BAR; MM(1, 1, bf1); VMC(6); BAR;
            // P5
            RD_A(1, 0); RD_B(1, 0, bf0); STAGE_A(0, 1, KAo(kn));
            BAR; LGKM; MM(0, 0, bf0); BAR;
            // P6
            RD_B(1, 1, bf1); STAGE_A(1, 0, KAo(km));
            BAR; LGKM; MM(0, 1, bf1); BAR;
            // P7
            RD_A(1, 1); STAGE_B(1, 0, KBo(km));
            BAR; LGKM; MM(1, 0, bf0); BAR;
            // P8
            STAGE_B(1, 1, KBo(km));
            BAR; MM(1, 1, bf1); VMC(6); BAR;
        }

        // epilogue: 32 dwordx4 stores; drain overlaps the bridge prefetch
        const int sb = s0 + mtl * 256 + wr * 128;
        #pragma unroll
        for (int n = 0; n < 4; ++n) {
            const int e = e0 + wc * 64 + n * 16 + eqb;
            const f32x4 bv4 = *(const f32x4*)&bias[eb * TDIM + e];
            #pragma unroll
            for (int m = 0; m < 8; ++m) {
                const int s = sb + m * 16 + cs;
                *(f32x4*)&out[(long)s * (TBZ * TDIM) + b * TDIM + e] = acc[m][n] + bv4;
            }
        }
        #pragma unroll
        for (int m = 0; m < 8; ++m)
            #pragma unroll
            for (int n = 0; n < 4; ++n)
                acc[m][n] = (f32x4){0.f, 0.f, 0.f, 0.f};
    }
#undef STAGE_A
#undef STAGE_B
#undef RD_A
#undef RD_B
#undef MM
}

// ---------- fallback: round-1 fused kernel ----------
__device__ inline unsigned short f2bf(float f) {
    union { float f; unsigned int u; } v; v.f = f;
    unsigned int r = v.u + 0x7fffu + ((v.u >> 16) & 1u);
    return (unsigned short)(r >> 16);
}
constexpr int FLDS = 40;

__global__ __launch_bounds__(256) void mapper_fused(
    const float* __restrict__ x, const int* __restrict__ lang_ids,
    const float* __restrict__ W, const float* __restrict__ bias,
    float* __restrict__ out)
{
    const int bid = blockIdx.x;
    const int b   = bid >> 7;
    const int t   = bid & 127;
    const int mt  = t >> 3;
    const int nt  = t & 7;
    const int s0  = mt * 128;
    const int e0  = nt * 128;
    const int tid = threadIdx.x;

    const int gid = 8 - lang_ids[b];
    const bool active = (gid >= 1) && (gid <= 8);
    int eb = gid - 1; eb = eb < 0 ? 0 : (eb > 7 ? 7 : eb);

    if (!active) {
        const f32x4* xs = (const f32x4*)x;
        f32x4*       os = (f32x4*)out;
        const int rs4 = TBZ * TDIM / 4;
        for (int i = tid; i < 128 * 128 / 4; i += 256) {
            int r = i >> 5, c = i & 31;
            long idx = (long)(s0 + r) * rs4 + b * (TDIM / 4) + (e0 >> 2) + c;
            os[idx] = xs[idx];
        }
        return;
    }

    __shared__ unsigned short As[128 * FLDS];
    __shared__ unsigned short Bs[128 * FLDS];
    const float* __restrict__ Wb = W + (long)eb * TDIM * TDIM;

    const int lane = tid & 63;
    const int wave = tid >> 6;
    const int wrr  = wave >> 1;
    const int wcc  = wave & 1;

    f32x4 acc[4][4];
    #pragma unroll
    for (int m = 0; m < 4; ++m)
        #pragma unroll
        for (int n = 0; n < 4; ++n)
            acc[m][n] = (f32x4){0.f, 0.f, 0.f, 0.f};

    const int rg = tid >> 3;
    const int cg = tid & 7;
    const int fr = lane & 15;
    const int fo = (lane >> 4) * 8;

    for (int k0 = 0; k0 < TDIM; k0 += 32) {
        __syncthreads();
        #pragma unroll
        for (int pp = 0; pp < 4; ++pp) {
            const int r = rg + pp * 32;
            f32x4 av = *(const f32x4*)(x  + (long)(s0 + r) * (TBZ * TDIM) + b * TDIM + k0 + cg * 4);
            f32x4 bv = *(const f32x4*)(Wb + (long)(e0 + r) * TDIM + k0 + cg * 4);
            unsigned int alo = (unsigned)f2bf(av.x) | ((unsigned)f2bf(av.y) << 16);
            unsigned int ahi = (unsigned)f2bf(av.z) | ((unsigned)f2bf(av.w) << 16);
            unsigned int blo = (unsigned)f2bf(bv.x) | ((unsigned)f2bf(bv.y) << 16);
            unsigned int bhi = (unsigned)f2bf(bv.z) | ((unsigned)f2bf(bv.w) << 16);
            *(uint2*)&As[r * FLDS + cg * 4] = make_uint2(alo, ahi);
            *(uint2*)&Bs[r * FLDS + cg * 4] = make_uint2(blo, bhi);
        }
        __syncthreads();

        bf16x8 af2[4], bfm[4];
        #pragma unroll
        for (int m = 0; m < 4; ++m)
            af2[m] = *(const bf16x8*)&As[(wrr * 64 + m * 16 + fr) * FLDS + fo];
        #pragma unroll
        for (int n = 0; n < 4; ++n)
            bfm[n] = *(const bf16x8*)&Bs[(wcc * 64 + n * 16 + fr) * FLDS + fo];
        #pragma unroll
        for (int m = 0; m < 4; ++m)
            #pragma unroll
            for (int n = 0; n < 4; ++n)
                acc[m][n] = __builtin_amdgcn_mfma_f32_16x16x32_bf16(af2[m], bfm[n], acc[m][n], 0, 0, 0);
    }

    const int cr = lane >> 4;
    const int cc2 = lane & 15;
    #pragma unroll
    for (int n = 0; n < 4; ++n) {
        const int e  = e0 + wcc * 64 + n * 16 + cc2;
        const float bv = bias[eb * TDIM + e];
        #pragma unroll
        for (int m = 0; m < 4; ++m) {
            #pragma unroll
            for (int j = 0; j < 4; ++j) {
                const int s = s0 + wrr * 64 + m * 16 + cr * 4 + j;
                out[(long)s * (TBZ * TDIM) + b * TDIM + e] = acc[m][n][j] + bv;
            }
        }
    }
}

extern "C" void kernel_launch(void* const* d_in, const int* in_sizes, int n_in,
                              void* d_out, int out_size, void* d_ws, size_t ws_size,
                              hipStream_t stream) {
    const float* x        = (const float*)d_in[0];
    const int*   lang_ids = (const int*)d_in[1];
    const float* W        = (const float*)d_in[2];
    const float* bias     = (const float*)d_in[3];
    float*       out      = (float*)d_out;

    const size_t xbytes = (size_t)TSEQ * TBZ * TDIM * 2;   // 128 MiB
    const size_t wbytes = (size_t)NLS * TDIM * TDIM * 2;   // 16 MiB

    if (ws_size >= xbytes + wbytes) {
        unsigned short* xbp = (unsigned short*)d_ws;
        unsigned short* wbp = (unsigned short*)((char*)d_ws + xbytes);
        conv_x<<<4096, 256, 0, stream>>>(x, xbp);
        conv_w<<<2048, 256, 0, stream>>>(W, wbp);
        mapper_gemm8p<<<512, 512, 0, stream>>>(xbp, lang_ids, wbp, bias, x, out);
    } else {
        mapper_fused<<<TBZ * 16 * 8, 256, 0, stream>>>(x, lang_ids, W, bias, out);
    }
}